// Round 8
// baseline (102.957 us; speedup 1.0000x reference)
//
#include <hip/hip_runtime.h>
#include <hip/hip_bf16.h>

#define NQ 12
typedef __hip_bfloat16 bf16;

__device__ __forceinline__ float b2f(unsigned int u) {
  union { unsigned int i; float f; } v; v.i = u << 16; return v.f;
}

// Dtype-adaptive scalar load (HW-proven: world is f32 in, but stay adaptive).
__device__ __forceinline__ float ldv(const void* p, int i, bool f32) {
  if (f32) return ((const float*)p)[i];
  return b2f((unsigned int)((const unsigned short*)p)[i]);
}

// Composite permutation of the 12 sequential ring CNOTs. HW-proven (R2/R7).
__device__ __forceinline__ int ringperm(int d) {
  int a = d ^ ((d & 1) << 11);
  return a ^ (a >> 1);
}

// Bank swizzle: GF(2)-linear involution mixing bits 5..9 into 0..4.
// All four access patterns below are <=2-way bank-aliased (free, m136):
// verified by rank analysis (each pattern's lane->bank map has kernel dim 1).
__device__ __forceinline__ int swz5(int p) { return p ^ ((p >> 5) & 31); }

// 128 threads (2 waves) per batch element; 32 amps/thread.
// Layout A: amp[j] = state[(j<<7)|t]  (qubits 0..4 <-> j bits 4..0;
//           qubit 5 <-> t bit6 (wave); qubits 6..11 <-> t bits 5..0)
// Layout B: amp[j] = state[(t<<5)|j]  (qubits 0..6 <-> t bits 6..0;
//           qubits 7..11 <-> j bits 4..0)
// Per layer: LDS pass (ring-CNOT perm + A->B), register RY q7..11,
// shfl RY q5,q6 (lane bits 1,0), LDS pass (B->A), register RY q0..4.
// All RYs within a layer commute -> exact.
__global__ __launch_bounds__(128) void qsim_kernel(
    const void* __restrict__ x,    // [B,12]
    const void* __restrict__ w,    // [2,12]
    const void* __restrict__ Wm,   // [2,12]
    const void* __restrict__ bv,   // [2]
    void* __restrict__ out)        // [B,2]
{
  __shared__ float st[4096];
  const int t = threadIdx.x;     // 0..127
  const int lane = t & 63;
  const int wave = t >> 6;
  const int b = blockIdx.x;

  // ---- inline dtype probe (HW-proven R5/R6/R7) ----
  bool f32;
  {
    const unsigned short* xu = (const unsigned short*)x;
    int insane = 0;
#pragma unroll
    for (int i = 0; i < 16; ++i) {
      float v = b2f((unsigned int)xu[2 * i]);
      float a = fabsf(v);
      if (!(a <= 64.f) || (a != 0.f && a < 1e-8f)) ++insane;
    }
    f32 = (insane >= 2);
  }

  // ---- init product state, layout A ----
  float lp = 1.f;
#pragma unroll
  for (int q = 5; q < 12; ++q) {
    float h = 0.5f * ldv(x, b * NQ + q, f32);
    lp *= ((t >> (11 - q)) & 1) ? __sinf(h) : __cosf(h);
  }
  float amp[32];
  amp[0] = lp;
#pragma unroll
  for (int q = 0; q < 5; ++q) {
    float h = 0.5f * ldv(x, b * NQ + q, f32);
    float c = __cosf(h), s = __sinf(h);
    const int m = 1 << (4 - q);
#pragma unroll
    for (int j = 0; j < 32; j += 2 * m) {
      float a0 = amp[j];
      amp[j]     = a0 * c;
      amp[j | m] = a0 * s;
    }
  }

  // per-thread swizzled address bases (sigma is linear: sigma(a^b)=sigma(a)^sigma(b))
  const int wA = swz5(t);                    // pass-1 write / pass-2 read base
  const int rB = swz5(ringperm(t << 5));     // pass-1 read base
  const int wB = swz5(t << 5);               // pass-2 write base

#pragma unroll 1
  for (int l = 0; l < 2; ++l) {
    // ---- Pass 1: ring-CNOT perm + transpose, A -> B ----
    __syncthreads();
#pragma unroll
    for (int j = 0; j < 32; ++j) st[swz5(j << 7) ^ wA] = amp[j];
    __syncthreads();
#pragma unroll
    for (int j = 0; j < 32; ++j) amp[j] = st[rB ^ swz5(ringperm(j))];

    // ---- RY q7..11 (register pairs in layout B) ----
#pragma unroll
    for (int q = 7; q < 12; ++q) {
      float h = 0.5f * ldv(w, l * NQ + q, f32);
      const float c = __cosf(h), s = __sinf(h);
      const int m = 1 << (11 - q);
#pragma unroll
      for (int j = 0; j < 32; ++j) {
        if (j & m) continue;
        float v0 = amp[j], v1 = amp[j | m];
        amp[j]     = fmaf(c, v0, -s * v1);
        amp[j | m] = fmaf(s, v0,  c * v1);
      }
    }
    // ---- RY q5 (lane bit1), q6 (lane bit0): in-wave shfl_xor ----
#pragma unroll
    for (int q = 5; q < 7; ++q) {
      float h = 0.5f * ldv(w, l * NQ + q, f32);
      const float c = __cosf(h), s = __sinf(h);
      const int lm = (q == 5) ? 2 : 1;
      const float se = (lane & lm) ? s : -s;
#pragma unroll
      for (int j = 0; j < 32; ++j) {
        float o = __shfl_xor(amp[j], lm, 64);
        amp[j] = fmaf(c, amp[j], se * o);
      }
    }

    // ---- Pass 2: pure transpose, B -> A ----
    __syncthreads();
#pragma unroll
    for (int j = 0; j < 32; ++j) st[wB ^ j] = amp[j];
    __syncthreads();
#pragma unroll
    for (int j = 0; j < 32; ++j) amp[j] = st[swz5(j << 7) ^ wA];

    // ---- RY q0..4 (register pairs in layout A) ----
#pragma unroll
    for (int q = 0; q < 5; ++q) {
      float h = 0.5f * ldv(w, l * NQ + q, f32);
      const float c = __cosf(h), s = __sinf(h);
      const int m = 1 << (4 - q);
#pragma unroll
      for (int j = 0; j < 32; ++j) {
        if (j & m) continue;
        float v0 = amp[j], v1 = amp[j | m];
        amp[j]     = fmaf(c, v0, -s * v1);
        amp[j | m] = fmaf(s, v0,  c * v1);
      }
    }
  }

  // ---- measurement in layout A ----
  float P = 0.f, z0 = 0.f, z1 = 0.f, z2 = 0.f, z3 = 0.f, z4 = 0.f;
#pragma unroll
  for (int j = 0; j < 32; ++j) {
    float pr = amp[j] * amp[j];
    P  += pr;
    z0 += (j & 16) ? -pr : pr;
    z1 += (j & 8)  ? -pr : pr;
    z2 += (j & 4)  ? -pr : pr;
    z3 += (j & 2)  ? -pr : pr;
    z4 += (j & 1)  ? -pr : pr;
  }

  // ---- fused head: per-thread partials, wave butterflies, LDS combine ----
  float acc0, acc1;
#pragma unroll
  for (int r = 0; r < 2; ++r) {
    float a = z0 * ldv(Wm, r * NQ + 0, f32) + z1 * ldv(Wm, r * NQ + 1, f32)
            + z2 * ldv(Wm, r * NQ + 2, f32) + z3 * ldv(Wm, r * NQ + 3, f32)
            + z4 * ldv(Wm, r * NQ + 4, f32);
    float ws = 0.f;
#pragma unroll
    for (int q = 5; q < 12; ++q) {
      float wv = ldv(Wm, r * NQ + q, f32);
      ws += ((t >> (11 - q)) & 1) ? -wv : wv;
    }
    float v = fmaf(P, ws, a);
    if (r == 0) acc0 = v; else acc1 = v;
  }
#pragma unroll
  for (int off = 32; off; off >>= 1) {
    acc0 += __shfl_xor(acc0, off, 64);
    acc1 += __shfl_xor(acc1, off, 64);
  }
  __syncthreads();                 // all pass-2 reads done; st reusable
  if (lane == 0) { st[wave * 2 + 0] = acc0; st[wave * 2 + 1] = acc1; }
  __syncthreads();
  if (t < 2) {
    float o = st[t] + st[2 + t] + ldv(bv, t, f32);
    if (f32) ((float*)out)[b * 2 + t] = o;
    else     ((bf16*)out)[b * 2 + t] = __float2bfloat16(o);
  }
}

extern "C" void kernel_launch(void* const* d_in, const int* in_sizes, int n_in,
                              void* d_out, int out_size, void* d_ws, size_t ws_size,
                              hipStream_t stream) {
  const void* x  = d_in[0];
  const void* w  = d_in[1];
  const void* Wm = d_in[2];
  const void* bv = d_in[3];
  const int batch = out_size / 2;   // out is [B, 2]
  qsim_kernel<<<dim3(batch), dim3(128), 0, stream>>>(x, w, Wm, bv, d_out);
}